// Round 4
// baseline (275.033 us; speedup 1.0000x reference)
//
#include <hip/hip_runtime.h>
#include <math.h>

#define N_NODES 20000
#define N_EDGES 320000
#define NG 64
#define NEG 0.2f
#define NCHUNK ((N_NODES + 255) / 256)   // 79

typedef __attribute__((ext_vector_type(8))) short bf16x8;
typedef __attribute__((ext_vector_type(4))) float f32x4;

__device__ __forceinline__ float bf2f(unsigned short u) {
  return __uint_as_float(((unsigned int)u) << 16);
}
__device__ __forceinline__ unsigned short f2bf(float f) {
  unsigned int u = __float_as_uint(f);
  return (unsigned short)((u + 0x7fffu + ((u >> 16) & 1u)) >> 16);
}

// ---------------------------------------------------------------------------
// k_prep: (A) wsall[20][64]: folded alpha weights; col c: set=c>>5,
// role=(c>>4)&1 (0=src,1=dst), head=c&15 ->  ws[k][c] = sum_j W[k][h*16+j]*a[h*16+j]
// (B) wpad[2][32][256]: W zero-padded to K=32.  (C) wffrag: Wf bf16 MFMA frags.
// ---------------------------------------------------------------------------
__global__ __launch_bounds__(256) void k_prep(
    const float* __restrict__ W_i, const float* __restrict__ as_i, const float* __restrict__ ad_i,
    const float* __restrict__ W_t, const float* __restrict__ as_t, const float* __restrict__ ad_t,
    const float* __restrict__ Wf,
    float* __restrict__ wsall, float* __restrict__ wpad, unsigned short* __restrict__ wffrag) {
  int idx = blockIdx.x * 256 + threadIdx.x;
  if (idx < 1280) {
    int k = idx >> 6, c = idx & 63;
    int set = c >> 5, role = (c >> 4) & 1, h = c & 15;
    const float* W = set ? W_t : W_i;
    const float* a = set ? (role ? ad_t : as_t) : (role ? ad_i : as_i);
    float v = 0.f;
#pragma unroll
    for (int j = 0; j < 16; ++j) v = fmaf(W[k * 256 + h * 16 + j], a[h * 16 + j], v);
    wsall[idx] = v;
    return;
  }
  idx -= 1280;
  if (idx < 16384) {
    int set = idx >> 13, rem = idx & 8191;
    int k = rem >> 8, c = rem & 255;
    const float* W = set ? W_t : W_i;
    wpad[idx] = (k < 20) ? W[k * 256 + c] : 0.f;
    return;
  }
  idx -= 16384;
  if (idx < 32768) {
    int j = idx & 7, lane = (idx >> 3) & 63, ks = (idx >> 9) & 15, ct = idx >> 13;
    int k = ks * 32 + (lane >> 4) * 8 + j;
    int nc = ct * 16 + (lane & 15);
    wffrag[idx] = f2bf(Wf[k * 64 + nc]);
  }
}

// ---------------------------------------------------------------------------
// k_alpha: 16 nodes/block. asrc/adst (both sets) = x @ wsall; also writes
// xpad [N][32] (x zero-padded).
// ---------------------------------------------------------------------------
__global__ __launch_bounds__(256) void k_alpha(
    const float* __restrict__ x, const float* __restrict__ wsall,
    float* __restrict__ xpad,
    float* __restrict__ asrc0, float* __restrict__ adst0,
    float* __restrict__ asrc1, float* __restrict__ adst1) {
  int t = threadIdx.x;
  int n0 = blockIdx.x * 16;
  __shared__ float xs[16][20];
  __shared__ float ws[20][64];
  for (int i = t; i < 16 * 20; i += 256) {
    int nd = i / 20, k = i % 20;
    xs[nd][k] = x[(n0 + nd) * 20 + k];
  }
  for (int i = t; i < 1280; i += 256) ws[i >> 6][i & 63] = wsall[i];
  __syncthreads();
  // xpad: 512 items
  for (int i = t; i < 512; i += 256) {
    int nd = i >> 5, j = i & 31;
    xpad[(size_t)(n0 + nd) * 32 + j] = (j < 20) ? xs[nd][j] : 0.f;
  }
  // alpha: 1024 items (16 nodes x 64 cols)
#pragma unroll
  for (int i = 0; i < 4; ++i) {
    int wi = i * 256 + t;
    int nd = wi >> 6, c = wi & 63;
    float v = 0.f;
#pragma unroll
    for (int k = 0; k < 20; ++k) v = fmaf(xs[nd][k], ws[k][c], v);
    int n = n0 + nd, h = c & 15;
    float* arr = (c >> 5) ? ((c >> 4) & 1 ? adst1 : asrc1)
                          : ((c >> 4) & 1 ? adst0 : asrc0);
    arr[n * 16 + h] = v;
  }
}

// ---------------------------------------------------------------------------
// CSR build
// ---------------------------------------------------------------------------
__global__ void k_hist(const int* __restrict__ ei0, const int* __restrict__ ei1,
                       int* __restrict__ cnt0, int* __restrict__ cnt1) {
  int e = blockIdx.x * blockDim.x + threadIdx.x;
  if (e >= N_EDGES) return;
  if (blockIdx.y == 0)
    atomicAdd(&cnt0[ei0[N_EDGES + e]], 1);
  else
    atomicAdd(&cnt1[ei1[N_EDGES + e]], 1);
}

__global__ __launch_bounds__(256) void k_scan1(
    const int* __restrict__ cnt0, const int* __restrict__ cnt1,
    int* __restrict__ tmp0, int* __restrict__ tmp1, int* __restrict__ csums) {
  int chunk = blockIdx.x, set = blockIdx.y;
  const int* cnt = set ? cnt1 : cnt0;
  int* tmp = set ? tmp1 : tmp0;
  int t = threadIdx.x, lane = t & 63, wv = t >> 6;
  int i = chunk * 256 + t;
  int v = (i < N_NODES) ? cnt[i] : 0;
  int s = v;
#pragma unroll
  for (int d = 1; d < 64; d <<= 1) {
    int o = __shfl_up(s, d);
    if (lane >= d) s += o;
  }
  __shared__ int wsum[4];
  if (lane == 63) wsum[wv] = s;
  __syncthreads();
  int pre = 0;
#pragma unroll
  for (int j = 0; j < 4; ++j)
    if (j < wv) pre += wsum[j];
  s += pre;
  if (i < N_NODES) tmp[i] = s;
  if (t == 255) csums[set * 128 + chunk] = s;
}

__global__ __launch_bounds__(128) void k_scan2(int* __restrict__ csums) {
  int set = blockIdx.x, t = threadIdx.x, lane = t & 63, wv = t >> 6;
  int v = (t < NCHUNK) ? csums[set * 128 + t] : 0;
  int s = v;
#pragma unroll
  for (int d = 1; d < 64; d <<= 1) {
    int o = __shfl_up(s, d);
    if (lane >= d) s += o;
  }
  __shared__ int ws2[2];
  if (lane == 63) ws2[wv] = s;
  __syncthreads();
  if (wv == 1) s += ws2[0];
  csums[set * 128 + t] = s - v;
}

__global__ __launch_bounds__(256) void k_scan3(
    const int* __restrict__ tmp0, const int* __restrict__ tmp1,
    const int* __restrict__ csums,
    int* __restrict__ rp0, int* __restrict__ rp1,
    int* __restrict__ fill0, int* __restrict__ fill1) {
  int chunk = blockIdx.x, set = blockIdx.y;
  const int* tmp = set ? tmp1 : tmp0;
  int* rp = set ? rp1 : rp0;
  int* fill = set ? fill1 : fill0;
  int i = chunk * 256 + threadIdx.x;
  if (i >= N_NODES) return;
  int off = csums[set * 128 + chunk];
  int incl = tmp[i];
  int c = fill[i];
  int excl = off + incl - c;
  rp[i] = excl;
  fill[i] = excl;
  if (i == N_NODES - 1) rp[N_NODES] = off + incl;
}

__global__ void k_scatter(const int* __restrict__ ei0, const int* __restrict__ ei1,
                          int* __restrict__ fill0, int* __restrict__ fill1,
                          int* __restrict__ srcs0, int* __restrict__ srcs1) {
  int e = blockIdx.x * blockDim.x + threadIdx.x;
  if (e >= N_EDGES) return;
  const int* ei = blockIdx.y ? ei1 : ei0;
  int* fill = blockIdx.y ? fill1 : fill0;
  int* srcs = blockIdx.y ? srcs1 : srcs0;
  int d = ei[N_EDGES + e];
  int pos = atomicAdd(&fill[d], 1);
  srcs[pos] = ei[e];
}

// ---------------------------------------------------------------------------
// k_gat: one wave per node, aggregation in x-space (rank-20 trick):
//   out[n,h,:] = (sum_e attn[e,h] * x[src_e,:]) @ W[:, h-block] + bias
// Edge loop: lane=(e4=lane>>4, h16=lane&15) computes exp(leaky(alpha)) for
// 4 edges x 16 heads; accumulation lane=(kq=lane>>4, h16) holds xagg[h16][kq*8..+7].
// All gathered data (xpad 2.5MB, asrc 1.3MB, wpad 32KB) is L2-resident.
// Projection: partner-exchange xagg across kq-quad (shfl_xor), each lane
// computes 4 channels, coalesced bf16 store. No LDS, no syncthreads.
// ---------------------------------------------------------------------------
__global__ __launch_bounds__(256) void k_gat(
    const float* __restrict__ xpad,
    const float* __restrict__ asrc0, const float* __restrict__ adst0,
    const float* __restrict__ asrc1, const float* __restrict__ adst1,
    const int* __restrict__ rp0, const int* __restrict__ srcs0,
    const int* __restrict__ rp1, const int* __restrict__ srcs1,
    const float* __restrict__ wpad,
    const float* __restrict__ bias0, const float* __restrict__ bias1,
    unsigned short* __restrict__ hcat) {
  int wv = threadIdx.x >> 6, lane = threadIdx.x & 63;
  int n = blockIdx.x * 4 + wv;
  int h16 = lane & 15, kq = lane >> 4;  // kq doubles as e4 in attn phase
  for (int g = 0; g < 2; ++g) {
    const float* asrc = g ? asrc1 : asrc0;
    const float* adst = g ? adst1 : adst0;
    const int* rp = g ? rp1 : rp0;
    const int* srcs = g ? srcs1 : srcs0;
    const float* wp = wpad + g * 8192;
    const float* bias = g ? bias1 : bias0;
    int k0 = rp[n], k1 = rp[n + 1];
    float adn = adst[n * 16 + h16];
    float lacc = 0.f;
    float xa[8];
#pragma unroll
    for (int j = 0; j < 8; ++j) xa[j] = 0.f;
    for (int base = k0; base < k1; base += 4) {
      int ne = k1 - base; if (ne > 4) ne = 4;
      float ex = 0.f;
      int s_a = 0;
      if (kq < ne) {
        s_a = srcs[base + kq];
        float a = asrc[s_a * 16 + h16] + adn;
        a = a >= 0.f ? a : NEG * a;
        ex = __expf(a);
      }
      lacc += ex;
      for (int e = 0; e < ne; ++e) {
        float w = __shfl(ex, e * 16 + h16);
        int s = __shfl(s_a, e * 16);
        const float4 va = *(const float4*)&xpad[(size_t)s * 32 + kq * 8];
        const float4 vb = *(const float4*)&xpad[(size_t)s * 32 + kq * 8 + 4];
        xa[0] = fmaf(w, va.x, xa[0]); xa[1] = fmaf(w, va.y, xa[1]);
        xa[2] = fmaf(w, va.z, xa[2]); xa[3] = fmaf(w, va.w, xa[3]);
        xa[4] = fmaf(w, vb.x, xa[4]); xa[5] = fmaf(w, vb.y, xa[5]);
        xa[6] = fmaf(w, vb.z, xa[6]); xa[7] = fmaf(w, vb.w, xa[7]);
      }
    }
    // denom for head h16 (sum over 4 e4 groups) -> all lanes
    float lh = lacc + __shfl_xor(lacc, 16);
    lh += __shfl_xor(lh, 32);
    float invl = lh > 0.f ? 1.f / lh : 0.f;
    // projection: lane computes channels c = kq*4..+3 of head h16.
    // xagg[h16][k], k=(kq^p)*8+j comes from partner lane^(p<<4).
    float pc0 = 0.f, pc1 = 0.f, pc2 = 0.f, pc3 = 0.f;
#pragma unroll
    for (int p = 0; p < 4; ++p) {
      float xb[8];
#pragma unroll
      for (int j = 0; j < 8; ++j) xb[j] = (p == 0) ? xa[j] : __shfl_xor(xa[j], p << 4);
      int kbase = (kq ^ p) * 8;
#pragma unroll
      for (int j = 0; j < 8; ++j) {
        const float4 wv4 = *(const float4*)&wp[(kbase + j) * 256 + h16 * 16 + kq * 4];
        pc0 = fmaf(xb[j], wv4.x, pc0);
        pc1 = fmaf(xb[j], wv4.y, pc1);
        pc2 = fmaf(xb[j], wv4.z, pc2);
        pc3 = fmaf(xb[j], wv4.w, pc3);
      }
    }
    const float4 b4 = *(const float4*)&bias[h16 * 16 + kq * 4];
    unsigned int u0 = (unsigned int)f2bf(fmaf(pc0, invl, b4.x)) |
                      ((unsigned int)f2bf(fmaf(pc1, invl, b4.y)) << 16);
    unsigned int u1 = (unsigned int)f2bf(fmaf(pc2, invl, b4.z)) |
                      ((unsigned int)f2bf(fmaf(pc3, invl, b4.w)) << 16);
    uint2 uv = {u0, u1};
    *(uint2*)&hcat[(size_t)n * 512 + g * 256 + h16 * 16 + kq * 4] = uv;
  }
}

// ---------------------------------------------------------------------------
// k_mlp: 64 nodes/block, layer 1 via bf16 MFMA, layers 2-4 scalar, pooled.
// ---------------------------------------------------------------------------
__global__ __launch_bounds__(256) void k_mlp(
    const unsigned short* __restrict__ hcat, const unsigned short* __restrict__ wffrag,
    const float* __restrict__ bf,
    const float* __restrict__ W1m, const float* __restrict__ b1v,
    const float* __restrict__ W2m, const float* __restrict__ b2v,
    const float* __restrict__ W3m, const float* __restrict__ b3v,
    const int* __restrict__ batch,
    float* __restrict__ gsum, int* __restrict__ gcnt) {
  int t = threadIdx.x, w = t >> 6, lane = t & 63;
  int n0 = blockIdx.x * 64;
  __shared__ float o1[64][68];
  __shared__ float o2[64][36];
  __shared__ float o3[64][20];
  __shared__ float o4[64][17];
  __shared__ int bs[64];
  if (t < 64) bs[t] = batch[min(n0 + t, N_NODES - 1)];

  {
    int m = lane & 15, kb = lane >> 4;
    int arow = n0 + w * 16 + m;
    if (arow >= N_NODES) arow = N_NODES - 1;
    const unsigned short* aptr = hcat + (size_t)arow * 512 + kb * 8;
    f32x4 acc0 = {0.f, 0.f, 0.f, 0.f}, acc1 = acc0, acc2 = acc0, acc3 = acc0;
#pragma unroll 4
    for (int ks = 0; ks < 16; ++ks) {
      bf16x8 af = *(const bf16x8*)(aptr + ks * 32);
      const unsigned short* bks = wffrag + (size_t)ks * 512 + lane * 8;
      bf16x8 b0 = *(const bf16x8*)(bks);
      bf16x8 b1 = *(const bf16x8*)(bks + 8192);
      bf16x8 b2 = *(const bf16x8*)(bks + 16384);
      bf16x8 b3 = *(const bf16x8*)(bks + 24576);
      acc0 = __builtin_amdgcn_mfma_f32_16x16x32_bf16(af, b0, acc0, 0, 0, 0);
      acc1 = __builtin_amdgcn_mfma_f32_16x16x32_bf16(af, b1, acc1, 0, 0, 0);
      acc2 = __builtin_amdgcn_mfma_f32_16x16x32_bf16(af, b2, acc2, 0, 0, 0);
      acc3 = __builtin_amdgcn_mfma_f32_16x16x32_bf16(af, b3, acc3, 0, 0, 0);
    }
    int col = lane & 15, rg = lane >> 4;
#pragma unroll
    for (int r = 0; r < 4; ++r) {
      int row = w * 16 + rg * 4 + r;
      o1[row][col]      = fmaxf(acc0[r] + bf[col], 0.f);
      o1[row][16 + col] = fmaxf(acc1[r] + bf[16 + col], 0.f);
      o1[row][32 + col] = fmaxf(acc2[r] + bf[32 + col], 0.f);
      o1[row][48 + col] = fmaxf(acc3[r] + bf[48 + col], 0.f);
    }
  }
  __syncthreads();
  int nd = t >> 2, qo = t & 3;
  {
    float a[8];
#pragma unroll
    for (int j = 0; j < 8; ++j) a[j] = b1v[qo * 8 + j];
#pragma unroll 4
    for (int k = 0; k < 64; ++k) {
      float hv = o1[nd][k];
      const float4 wA = *(const float4*)&W1m[k * 32 + qo * 8];
      const float4 wB = *(const float4*)&W1m[k * 32 + qo * 8 + 4];
      a[0] = fmaf(hv, wA.x, a[0]); a[1] = fmaf(hv, wA.y, a[1]);
      a[2] = fmaf(hv, wA.z, a[2]); a[3] = fmaf(hv, wA.w, a[3]);
      a[4] = fmaf(hv, wB.x, a[4]); a[5] = fmaf(hv, wB.y, a[5]);
      a[6] = fmaf(hv, wB.z, a[6]); a[7] = fmaf(hv, wB.w, a[7]);
    }
#pragma unroll
    for (int j = 0; j < 8; ++j) o2[nd][qo * 8 + j] = fmaxf(a[j], 0.f);
  }
  __syncthreads();
  {
    float a[4];
    const float4 bb = *(const float4*)&b2v[qo * 4];
    a[0] = bb.x; a[1] = bb.y; a[2] = bb.z; a[3] = bb.w;
#pragma unroll 4
    for (int k = 0; k < 32; ++k) {
      float hv = o2[nd][k];
      const float4 ww = *(const float4*)&W2m[k * 16 + qo * 4];
      a[0] = fmaf(hv, ww.x, a[0]); a[1] = fmaf(hv, ww.y, a[1]);
      a[2] = fmaf(hv, ww.z, a[2]); a[3] = fmaf(hv, ww.w, a[3]);
    }
#pragma unroll
    for (int j = 0; j < 4; ++j) o3[nd][qo * 4 + j] = fmaxf(a[j], 0.f);
  }
  __syncthreads();
  {
    float a[4];
    const float4 bb = *(const float4*)&b3v[qo * 4];
    a[0] = bb.x; a[1] = bb.y; a[2] = bb.z; a[3] = bb.w;
#pragma unroll
    for (int k = 0; k < 16; ++k) {
      float hv = o3[nd][k];
      const float4 ww = *(const float4*)&W3m[k * 16 + qo * 4];
      a[0] = fmaf(hv, ww.x, a[0]); a[1] = fmaf(hv, ww.y, a[1]);
      a[2] = fmaf(hv, ww.z, a[2]); a[3] = fmaf(hv, ww.w, a[3]);
    }
#pragma unroll
    for (int j = 0; j < 4; ++j) o4[nd][qo * 4 + j] = fmaxf(a[j], 0.f);
  }
  __syncthreads();
  if (t < 128) {
    int s = t >> 4, js = t & 15;
    int b = bs[0] + s;
    if (b <= bs[63]) {
      float sum = 0.f; int c = 0;
#pragma unroll 8
      for (int ndd = 0; ndd < 64; ++ndd) {
        if (n0 + ndd < N_NODES && bs[ndd] == b) { sum += o4[ndd][js]; ++c; }
      }
      if (c > 0) {
        atomicAdd(&gsum[b * 16 + js], sum);
        if (js == 0) atomicAdd(&gcnt[b], c);
      }
    }
  }
}

__global__ void k_head(const float* __restrict__ gsum, const int* __restrict__ gcnt,
                       const float* __restrict__ Wce, const float* __restrict__ bce,
                       const float* __restrict__ Wcv, const float* __restrict__ bcv,
                       float* __restrict__ out) {
  int t = threadIdx.x;
  if (t >= 384) return;
  int half = t / 192, idx = t % 192;
  int b = idx / 3, r = idx % 3;
  float cnt = (float)gcnt[b];
  float inv = cnt > 0.f ? 1.f / cnt : 1.f;
  const float* Wc = half ? Wcv : Wce;
  const float* bc = half ? bcv : bce;
  float v = bc[r];
#pragma unroll
  for (int j = 0; j < 16; ++j) v = fmaf(gsum[b * 16 + j] * inv, Wc[j * 3 + r], v);
  out[t] = v;
}

extern "C" void kernel_launch(void* const* d_in, const int* in_sizes, int n_in,
                              void* d_out, int out_size, void* d_ws, size_t ws_size,
                              hipStream_t stream) {
  const float* x = (const float*)d_in[0];
  const int* ei_i = (const int*)d_in[1];
  const int* ei_t = (const int*)d_in[3];
  const int* batch = (const int*)d_in[5];
  const float* W_i = (const float*)d_in[6];
  const float* as_i = (const float*)d_in[7];
  const float* ad_i = (const float*)d_in[8];
  const float* b_i = (const float*)d_in[9];
  const float* W_t = (const float*)d_in[10];
  const float* as_t = (const float*)d_in[11];
  const float* ad_t = (const float*)d_in[12];
  const float* b_t = (const float*)d_in[13];
  const float* Wf = (const float*)d_in[14];
  const float* bf = (const float*)d_in[15];
  const float* W1 = (const float*)d_in[16];
  const float* b1 = (const float*)d_in[17];
  const float* W2 = (const float*)d_in[18];
  const float* b2 = (const float*)d_in[19];
  const float* W3 = (const float*)d_in[20];
  const float* b3 = (const float*)d_in[21];
  const float* Wce = (const float*)d_in[22];
  const float* bce = (const float*)d_in[23];
  const float* Wcv = (const float*)d_in[24];
  const float* bcv = (const float*)d_in[25];

  char* ws = (char*)d_ws;
  size_t off = 0;
  auto take = [&](size_t bytes) {
    void* p = ws + off;
    off = (off + bytes + 255) & ~(size_t)255;
    return p;
  };
  float* xpad = (float*)take((size_t)N_NODES * 32 * 4);
  unsigned short* hcat = (unsigned short*)take((size_t)N_NODES * 512 * 2);
  float* wsall = (float*)take((size_t)1280 * 4);
  float* wpad = (float*)take((size_t)2 * 32 * 256 * 4);
  unsigned short* wffrag = (unsigned short*)take((size_t)4 * 16 * 64 * 8 * 2);
  float* asrc_i = (float*)take((size_t)N_NODES * 16 * 4);
  float* adst_i = (float*)take((size_t)N_NODES * 16 * 4);
  float* asrc_t = (float*)take((size_t)N_NODES * 16 * 4);
  float* adst_t = (float*)take((size_t)N_NODES * 16 * 4);
  int* rowptr_i = (int*)take((size_t)(N_NODES + 1) * 4);
  int* rowptr_t = (int*)take((size_t)(N_NODES + 1) * 4);
  int* fill_i = (int*)take((size_t)N_NODES * 4);
  int* fill_t = (int*)take((size_t)N_NODES * 4);
  int* tmp_i = (int*)take((size_t)N_NODES * 4);
  int* tmp_t = (int*)take((size_t)N_NODES * 4);
  int* csums = (int*)take((size_t)2 * 128 * 4);
  int* srcs_i = (int*)take((size_t)N_EDGES * 4);
  int* srcs_t = (int*)take((size_t)N_EDGES * 4);
  float* gsum = (float*)take((size_t)NG * 16 * 4);
  int* gcnt = (int*)take((size_t)NG * 4);

  hipMemsetAsync(fill_i, 0, (size_t)N_NODES * 4, stream);
  hipMemsetAsync(fill_t, 0, (size_t)N_NODES * 4, stream);
  hipMemsetAsync(gsum, 0, (size_t)NG * 16 * 4, stream);
  hipMemsetAsync(gcnt, 0, (size_t)NG * 4, stream);

  k_prep<<<197, 256, 0, stream>>>(W_i, as_i, ad_i, W_t, as_t, ad_t, Wf,
                                  wsall, wpad, wffrag);
  k_alpha<<<N_NODES / 16, 256, 0, stream>>>(x, wsall, xpad,
                                            asrc_i, adst_i, asrc_t, adst_t);

  dim3 egrid((N_EDGES + 255) / 256, 2);
  k_hist<<<egrid, 256, 0, stream>>>(ei_i, ei_t, fill_i, fill_t);
  dim3 sgrid(NCHUNK, 2);
  k_scan1<<<sgrid, 256, 0, stream>>>(fill_i, fill_t, tmp_i, tmp_t, csums);
  k_scan2<<<2, 128, 0, stream>>>(csums);
  k_scan3<<<sgrid, 256, 0, stream>>>(tmp_i, tmp_t, csums, rowptr_i, rowptr_t,
                                     fill_i, fill_t);
  k_scatter<<<egrid, 256, 0, stream>>>(ei_i, ei_t, fill_i, fill_t, srcs_i, srcs_t);

  k_gat<<<N_NODES / 4, 256, 0, stream>>>(xpad, asrc_i, adst_i, asrc_t, adst_t,
                                         rowptr_i, srcs_i, rowptr_t, srcs_t,
                                         wpad, b_i, b_t, hcat);

  k_mlp<<<(N_NODES + 63) / 64, 256, 0, stream>>>(hcat, wffrag, bf, W1, b1, W2, b2,
                                                 W3, b3, batch, gsum, gcnt);

  k_head<<<1, 384, 0, stream>>>(gsum, gcnt, Wce, bce, Wcv, bcv, (float*)d_out);
}

// Round 5
// 211.201 us; speedup vs baseline: 1.3022x; 1.3022x over previous
//
#include <hip/hip_runtime.h>
#include <math.h>

#define N_NODES 20000
#define N_EDGES 320000
#define NG 64
#define NEG 0.2f
#define NCHUNK ((N_NODES + 255) / 256)   // 79

typedef __attribute__((ext_vector_type(8))) short bf16x8;
typedef __attribute__((ext_vector_type(4))) float f32x4;

__device__ __forceinline__ unsigned short f2bf(float f) {
  unsigned int u = __float_as_uint(f);
  return (unsigned short)((u + 0x7fffu + ((u >> 16) & 1u)) >> 16);
}

// ---------------------------------------------------------------------------
// k_prep (one kernel, index ranges):
//  [0,1280)        wsall[20][64]: folded alpha weights (set, role, head)
//  [..+49152)      wbigfrag: bf16 MFMA B-fragments of Wbig[768][64],
//                  Wbig[(g,h,c)][j] = sum_m W_g[c][h*16+m] * Wf[g*256+h*16+m][j]
//                  (c>=20 rows are zero padding; frag[ct][ks][lane][8])
//  [..+64)         bfold[64] = bf + concat(b_i,b_t) @ Wf
//  [..+20000)x2    zero fill_i / fill_t (hist counters)
//  [..+1024+64)    zero gsum / gcnt
// ---------------------------------------------------------------------------
__global__ __launch_bounds__(256) void k_prep(
    const float* __restrict__ W_i, const float* __restrict__ as_i, const float* __restrict__ ad_i,
    const float* __restrict__ W_t, const float* __restrict__ as_t, const float* __restrict__ ad_t,
    const float* __restrict__ Wf, const float* __restrict__ bf,
    const float* __restrict__ b_i, const float* __restrict__ b_t,
    float* __restrict__ wsall, unsigned short* __restrict__ wbigfrag,
    float* __restrict__ bfold,
    int* __restrict__ fill_i, int* __restrict__ fill_t,
    float* __restrict__ gsum, int* __restrict__ gcnt) {
  int idx = blockIdx.x * 256 + threadIdx.x;
  if (idx < 1280) {
    int k = idx >> 6, c = idx & 63;
    int set = c >> 5, role = (c >> 4) & 1, h = c & 15;
    const float* W = set ? W_t : W_i;
    const float* a = set ? (role ? ad_t : as_t) : (role ? ad_i : as_i);
    float v = 0.f;
#pragma unroll
    for (int j = 0; j < 16; ++j) v = fmaf(W[k * 256 + h * 16 + j], a[h * 16 + j], v);
    wsall[idx] = v;
    return;
  }
  idx -= 1280;
  if (idx < 49152) {
    int ct = idx / 12288, rem = idx % 12288;
    int lane = (rem >> 3) & 63, j = rem & 7, ks = rem >> 9;
    int k = ks * 32 + ((lane >> 4) << 3) + j;
    int nc = ct * 16 + (lane & 15);
    float v = 0.f;
    int g = (k >= 384) ? 1 : 0;
    int r = k - g * 384;
    int h = r / 24, c = r - h * 24;
    if (c < 20) {
      const float* W = g ? W_t : W_i;
      const float* wr = W + c * 256 + (h << 4);
      const float* wf = Wf + ((g << 8) + (h << 4)) * 64 + nc;
#pragma unroll
      for (int m = 0; m < 16; ++m) v = fmaf(wr[m], wf[m * 64], v);
    }
    wbigfrag[idx] = f2bf(v);
    return;
  }
  idx -= 49152;
  if (idx < 64) {
    float v = bf[idx];
    for (int i = 0; i < 256; ++i) v = fmaf(b_i[i], Wf[i * 64 + idx], v);
    for (int i = 0; i < 256; ++i) v = fmaf(b_t[i], Wf[(256 + i) * 64 + idx], v);
    bfold[idx] = v;
    return;
  }
  idx -= 64;
  if (idx < N_NODES) { fill_i[idx] = 0; return; }
  idx -= N_NODES;
  if (idx < N_NODES) { fill_t[idx] = 0; return; }
  idx -= N_NODES;
  if (idx < NG * 16) { gsum[idx] = 0.f; return; }
  idx -= NG * 16;
  if (idx < NG) gcnt[idx] = 0;
}

// ---------------------------------------------------------------------------
// k_alpha: 16 nodes/block. asrc/adst (both sets) = x @ wsall; writes xpad.
// ---------------------------------------------------------------------------
__global__ __launch_bounds__(256) void k_alpha(
    const float* __restrict__ x, const float* __restrict__ wsall,
    float* __restrict__ xpad,
    float* __restrict__ asrc0, float* __restrict__ adst0,
    float* __restrict__ asrc1, float* __restrict__ adst1) {
  int t = threadIdx.x;
  int n0 = blockIdx.x * 16;
  __shared__ float xs[16][20];
  __shared__ float ws[20][64];
  for (int i = t; i < 16 * 20; i += 256) {
    int nd = i / 20, k = i % 20;
    xs[nd][k] = x[(n0 + nd) * 20 + k];
  }
  for (int i = t; i < 1280; i += 256) ws[i >> 6][i & 63] = wsall[i];
  __syncthreads();
  for (int i = t; i < 512; i += 256) {
    int nd = i >> 5, j = i & 31;
    xpad[(size_t)(n0 + nd) * 32 + j] = (j < 20) ? xs[nd][j] : 0.f;
  }
#pragma unroll
  for (int i = 0; i < 4; ++i) {
    int wi = i * 256 + t;
    int nd = wi >> 6, c = wi & 63;
    float v = 0.f;
#pragma unroll
    for (int k = 0; k < 20; ++k) v = fmaf(xs[nd][k], ws[k][c], v);
    int n = n0 + nd, h = c & 15;
    float* arr = (c >> 5) ? ((c >> 4) & 1 ? adst1 : asrc1)
                          : ((c >> 4) & 1 ? adst0 : asrc0);
    arr[n * 16 + h] = v;
  }
}

// ---------------------------------------------------------------------------
// CSR build
// ---------------------------------------------------------------------------
__global__ void k_hist(const int* __restrict__ ei0, const int* __restrict__ ei1,
                       int* __restrict__ cnt0, int* __restrict__ cnt1) {
  int e = blockIdx.x * blockDim.x + threadIdx.x;
  if (e >= N_EDGES) return;
  if (blockIdx.y == 0)
    atomicAdd(&cnt0[ei0[N_EDGES + e]], 1);
  else
    atomicAdd(&cnt1[ei1[N_EDGES + e]], 1);
}

// pass 1: per-chunk inclusive scan -> tmp, chunk totals -> csums
__global__ __launch_bounds__(256) void k_scan1(
    const int* __restrict__ cnt0, const int* __restrict__ cnt1,
    int* __restrict__ tmp0, int* __restrict__ tmp1, int* __restrict__ csums) {
  int chunk = blockIdx.x, set = blockIdx.y;
  const int* cnt = set ? cnt1 : cnt0;
  int* tmp = set ? tmp1 : tmp0;
  int t = threadIdx.x, lane = t & 63, wv = t >> 6;
  int i = chunk * 256 + t;
  int v = (i < N_NODES) ? cnt[i] : 0;
  int s = v;
#pragma unroll
  for (int d = 1; d < 64; d <<= 1) {
    int o = __shfl_up(s, d);
    if (lane >= d) s += o;
  }
  __shared__ int wsum[4];
  if (lane == 63) wsum[wv] = s;
  __syncthreads();
  int pre = 0;
#pragma unroll
  for (int j = 0; j < 4; ++j)
    if (j < wv) pre += wsum[j];
  s += pre;
  if (i < N_NODES) tmp[i] = s;
  if (t == 255) csums[set * 128 + chunk] = s;
}

// pass 2 (fused): per-block serial prefix of chunk totals, then rowptr/fill.
__global__ __launch_bounds__(256) void k_scan3(
    const int* __restrict__ tmp0, const int* __restrict__ tmp1,
    const int* __restrict__ csums,
    int* __restrict__ rp0, int* __restrict__ rp1,
    int* __restrict__ fill0, int* __restrict__ fill1) {
  int chunk = blockIdx.x, set = blockIdx.y;
  const int* tmp = set ? tmp1 : tmp0;
  int* rp = set ? rp1 : rp0;
  int* fill = set ? fill1 : fill0;
  __shared__ int soff;
  if (threadIdx.x == 0) {
    int acc = 0;
    for (int cc = 0; cc < chunk; ++cc) acc += csums[set * 128 + cc];
    soff = acc;
  }
  __syncthreads();
  int off = soff;
  int i = chunk * 256 + threadIdx.x;
  if (i >= N_NODES) return;
  int incl = tmp[i];
  int c = fill[i];  // fill still holds counts
  int excl = off + incl - c;
  rp[i] = excl;
  fill[i] = excl;
  if (i == N_NODES - 1) rp[N_NODES] = off + incl;
}

__global__ void k_scatter(const int* __restrict__ ei0, const int* __restrict__ ei1,
                          int* __restrict__ fill0, int* __restrict__ fill1,
                          int* __restrict__ srcs0, int* __restrict__ srcs1) {
  int e = blockIdx.x * blockDim.x + threadIdx.x;
  if (e >= N_EDGES) return;
  const int* ei = blockIdx.y ? ei1 : ei0;
  int* fill = blockIdx.y ? fill1 : fill0;
  int* srcs = blockIdx.y ? srcs1 : srcs0;
  int d = ei[N_EDGES + e];
  int pos = atomicAdd(&fill[d], 1);
  srcs[pos] = ei[e];
}

// ---------------------------------------------------------------------------
// k_gat: one wave per node, x-space aggregation, NO projection (folded into
// Wbig). Per 4-edge batch: lane (e4,h16) loads srcs/asrc/one float2 of xpad
// (128B/edge, fully coalesced, L2-resident); next batch prefetched before
// compute. Attn w and x chunks redistributed via shfl (ds_bpermute).
// Inner loop branch-free: invalid edges have ex=0 => contribute nothing.
// Writes normalized xagg (bf16, [N][2][16][24]) = 768 cols/node.
// ---------------------------------------------------------------------------
__global__ __launch_bounds__(256) void k_gat(
    const float* __restrict__ xpad,
    const float* __restrict__ asrc0, const float* __restrict__ adst0,
    const float* __restrict__ asrc1, const float* __restrict__ adst1,
    const int* __restrict__ rp0, const int* __restrict__ srcs0,
    const int* __restrict__ rp1, const int* __restrict__ srcs1,
    unsigned short* __restrict__ xagg) {
  int wv = threadIdx.x >> 6, lane = threadIdx.x & 63;
  int n = blockIdx.x * 4 + wv;
  int h16 = lane & 15, e4 = lane >> 4;
  for (int g = 0; g < 2; ++g) {
    const float* asrc = g ? asrc1 : asrc0;
    const float* adst = g ? adst1 : adst0;
    const int* rp = g ? rp1 : rp0;
    const int* srcs = g ? srcs1 : srcs0;
    int k0 = rp[n], k1 = rp[n + 1];
    float adn = adst[n * 16 + h16];
    float lacc = 0.f;
    float xa[8];
#pragma unroll
    for (int j = 0; j < 8; ++j) xa[j] = 0.f;
    if (k1 > k0) {
      // prologue: batch 0 loads (clamped indices; invalid lanes masked later)
      int s = srcs[min(k0 + e4, k1 - 1)];
      float av = asrc[s * 16 + h16];
      float2 xv = *(const float2*)&xpad[(size_t)s * 32 + h16 * 2];
      for (int base = k0; base < k1; base += 4) {
        bool more = (base + 4) < k1;
        int sN = 0; float avN = 0.f; float2 xvN; xvN.x = 0.f; xvN.y = 0.f;
        if (more) {  // prefetch next batch before current compute
          sN = srcs[min(base + 4 + e4, k1 - 1)];
          avN = asrc[sN * 16 + h16];
          xvN = *(const float2*)&xpad[(size_t)sN * 32 + h16 * 2];
        }
        float a = av + adn;
        a = a >= 0.f ? a : NEG * a;
        float ex = (base + e4 < k1) ? __expf(a) : 0.f;
        lacc += ex;
#pragma unroll
        for (int e = 0; e < 4; ++e) {
          float w = __shfl(ex, e * 16 + h16);
#pragma unroll
          for (int j2 = 0; j2 < 4; ++j2) {
            int sl = e * 16 + e4 * 4 + j2;
            float xx = __shfl(xv.x, sl);
            float xy = __shfl(xv.y, sl);
            xa[j2 * 2]     = fmaf(w, xx, xa[j2 * 2]);
            xa[j2 * 2 + 1] = fmaf(w, xy, xa[j2 * 2 + 1]);
          }
        }
        av = avN; xv = xvN; s = sN;
      }
    }
    // per-head denom: sum over the 4 e4-groups
    float lh = lacc + __shfl_xor(lacc, 16);
    lh += __shfl_xor(lh, 32);
    float invl = lh > 0.f ? 1.f / lh : 0.f;
    // store 8 normalized bf16 channels (c = e4*8..+7; c>=20 are zeros)
    if (e4 < 3) {
      unsigned int u[4];
#pragma unroll
      for (int q = 0; q < 4; ++q)
        u[q] = (unsigned int)f2bf(xa[2 * q] * invl) |
               ((unsigned int)f2bf(xa[2 * q + 1] * invl) << 16);
      *(uint4*)&xagg[(size_t)n * 768 + g * 384 + h16 * 24 + e4 * 8] = *(uint4*)u;
    }
  }
}

// ---------------------------------------------------------------------------
// k_mlp: 64 nodes/block. Layer 1: [N,768]@Wbig via bf16 MFMA (24 K-steps,
// 4 col-tiles). Layers 2-4 scalar from LDS; pool via per-block atomics.
// ---------------------------------------------------------------------------
__global__ __launch_bounds__(256) void k_mlp(
    const unsigned short* __restrict__ xagg, const unsigned short* __restrict__ wbigfrag,
    const float* __restrict__ bfold,
    const float* __restrict__ W1m, const float* __restrict__ b1v,
    const float* __restrict__ W2m, const float* __restrict__ b2v,
    const float* __restrict__ W3m, const float* __restrict__ b3v,
    const int* __restrict__ batch,
    float* __restrict__ gsum, int* __restrict__ gcnt) {
  int t = threadIdx.x, w = t >> 6, lane = t & 63;
  int n0 = blockIdx.x * 64;
  __shared__ float o1[64][68];
  __shared__ float o2[64][36];
  __shared__ float o3[64][20];
  __shared__ float o4[64][17];
  __shared__ int bs[64];
  if (t < 64) bs[t] = batch[min(n0 + t, N_NODES - 1)];

  {
    int m = lane & 15, kb = lane >> 4;
    int arow = n0 + w * 16 + m;
    if (arow >= N_NODES) arow = N_NODES - 1;
    const unsigned short* aptr = xagg + (size_t)arow * 768 + kb * 8;
    f32x4 acc0 = {0.f, 0.f, 0.f, 0.f}, acc1 = acc0, acc2 = acc0, acc3 = acc0;
#pragma unroll 4
    for (int ks = 0; ks < 24; ++ks) {
      bf16x8 af = *(const bf16x8*)(aptr + ks * 32);
      const unsigned short* bks = wbigfrag + (size_t)ks * 512 + lane * 8;
      bf16x8 b0 = *(const bf16x8*)(bks);
      bf16x8 b1 = *(const bf16x8*)(bks + 12288);
      bf16x8 b2 = *(const bf16x8*)(bks + 24576);
      bf16x8 b3 = *(const bf16x8*)(bks + 36864);
      acc0 = __builtin_amdgcn_mfma_f32_16x16x32_bf16(af, b0, acc0, 0, 0, 0);
      acc1 = __builtin_amdgcn_mfma_f32_16x16x32_bf16(af, b1, acc1, 0, 0, 0);
      acc2 = __builtin_amdgcn_mfma_f32_16x16x32_bf16(af, b2, acc2, 0, 0, 0);
      acc3 = __builtin_amdgcn_mfma_f32_16x16x32_bf16(af, b3, acc3, 0, 0, 0);
    }
    int col = lane & 15, rg = lane >> 4;
#pragma unroll
    for (int r = 0; r < 4; ++r) {
      int row = w * 16 + rg * 4 + r;
      o1[row][col]      = fmaxf(acc0[r] + bfold[col], 0.f);
      o1[row][16 + col] = fmaxf(acc1[r] + bfold[16 + col], 0.f);
      o1[row][32 + col] = fmaxf(acc2[r] + bfold[32 + col], 0.f);
      o1[row][48 + col] = fmaxf(acc3[r] + bfold[48 + col], 0.f);
    }
  }
  __syncthreads();
  int nd = t >> 2, qo = t & 3;
  {
    float a[8];
#pragma unroll
    for (int j = 0; j < 8; ++j) a[j] = b1v[qo * 8 + j];
#pragma unroll 4
    for (int k = 0; k < 64; ++k) {
      float hv = o1[nd][k];
      const float4 wA = *(const float4*)&W1m[k * 32 + qo * 8];
      const float4 wB = *(const float4*)&W1m[k * 32 + qo * 8 + 4];
      a[0] = fmaf(hv, wA.x, a[0]); a[1] = fmaf(hv, wA.y, a[1]);
      a[2] = fmaf(hv, wA.z, a[2]); a[3] = fmaf(hv, wA.w, a[3]);
      a[4] = fmaf(hv, wB.x, a[4]); a[5] = fmaf(hv, wB.y, a[5]);
      a[6] = fmaf(hv, wB.z, a[6]); a[7] = fmaf(hv, wB.w, a[7]);
    }
#pragma unroll
    for (int j = 0; j < 8; ++j) o2[nd][qo * 8 + j] = fmaxf(a[j], 0.f);
  }
  __syncthreads();
  {
    float a[4];
    const float4 bb = *(const float4*)&b2v[qo * 4];
    a[0] = bb.x; a[1] = bb.y; a[2] = bb.z; a[3] = bb.w;
#pragma unroll 4
    for (int k = 0; k < 32; ++k) {
      float hv = o2[nd][k];
      const float4 ww = *(const float4*)&W2m[k * 16 + qo * 4];
      a[0] = fmaf(hv, ww.x, a[0]); a[1] = fmaf(hv, ww.y, a[1]);
      a[2] = fmaf(hv, ww.z, a[2]); a[3] = fmaf(hv, ww.w, a[3]);
    }
#pragma unroll
    for (int j = 0; j < 4; ++j) o3[nd][qo * 4 + j] = fmaxf(a[j], 0.f);
  }
  __syncthreads();
  {
    float a[4];
    const float4 bb = *(const float4*)&b3v[qo * 4];
    a[0] = bb.x; a[1] = bb.y; a[2] = bb.z; a[3] = bb.w;
#pragma unroll
    for (int k = 0; k < 16; ++k) {
      float hv = o3[nd][k];
      const float4 ww = *(const float4*)&W3m[k * 16 + qo * 4];
      a[0] = fmaf(hv, ww.x, a[0]); a[1] = fmaf(hv, ww.y, a[1]);
      a[2] = fmaf(hv, ww.z, a[2]); a[3] = fmaf(hv, ww.w, a[3]);
    }
#pragma unroll
    for (int j = 0; j < 4; ++j) o4[nd][qo * 4 + j] = fmaxf(a[j], 0.f);
  }
  __syncthreads();
  if (t < 128) {
    int s = t >> 4, js = t & 15;
    int b = bs[0] + s;
    if (b <= bs[63]) {
      float sum = 0.f; int c = 0;
#pragma unroll 8
      for (int ndd = 0; ndd < 64; ++ndd) {
        if (n0 + ndd < N_NODES && bs[ndd] == b) { sum += o4[ndd][js]; ++c; }
      }
      if (c > 0) {
        atomicAdd(&gsum[b * 16 + js], sum);
        if (js == 0) atomicAdd(&gcnt[b], c);
      }
    }
  }
}

__global__ void k_head(const float* __restrict__ gsum, const int* __restrict__ gcnt,
                       const float* __restrict__ Wce, const float* __restrict__ bce,
                       const float* __restrict__ Wcv, const float* __restrict__ bcv,
                       float* __restrict__ out) {
  int t = threadIdx.x;
  if (t >= 384) return;
  int half = t / 192, idx = t % 192;
  int b = idx / 3, r = idx % 3;
  float cnt = (float)gcnt[b];
  float inv = cnt > 0.f ? 1.f / cnt : 1.f;
  const float* Wc = half ? Wcv : Wce;
  const float* bc = half ? bcv : bce;
  float v = bc[r];
#pragma unroll
  for (int j = 0; j < 16; ++j) v = fmaf(gsum[b * 16 + j] * inv, Wc[j * 3 + r], v);
  out[t] = v;
}

extern "C" void kernel_launch(void* const* d_in, const int* in_sizes, int n_in,
                              void* d_out, int out_size, void* d_ws, size_t ws_size,
                              hipStream_t stream) {
  const float* x = (const float*)d_in[0];
  const int* ei_i = (const int*)d_in[1];
  const int* ei_t = (const int*)d_in[3];
  const int* batch = (const int*)d_in[5];
  const float* W_i = (const float*)d_in[6];
  const float* as_i = (const float*)d_in[7];
  const float* ad_i = (const float*)d_in[8];
  const float* b_i = (const float*)d_in[9];
  const float* W_t = (const float*)d_in[10];
  const float* as_t = (const float*)d_in[11];
  const float* ad_t = (const float*)d_in[12];
  const float* b_t = (const float*)d_in[13];
  const float* Wf = (const float*)d_in[14];
  const float* bf = (const float*)d_in[15];
  const float* W1 = (const float*)d_in[16];
  const float* b1 = (const float*)d_in[17];
  const float* W2 = (const float*)d_in[18];
  const float* b2 = (const float*)d_in[19];
  const float* W3 = (const float*)d_in[20];
  const float* b3 = (const float*)d_in[21];
  const float* Wce = (const float*)d_in[22];
  const float* bce = (const float*)d_in[23];
  const float* Wcv = (const float*)d_in[24];
  const float* bcv = (const float*)d_in[25];

  char* ws = (char*)d_ws;
  size_t off = 0;
  auto take = [&](size_t bytes) {
    void* p = ws + off;
    off = (off + bytes + 255) & ~(size_t)255;
    return p;
  };
  float* xpad = (float*)take((size_t)N_NODES * 32 * 4);
  unsigned short* xagg = (unsigned short*)take((size_t)N_NODES * 768 * 2);
  float* wsall = (float*)take((size_t)1280 * 4);
  unsigned short* wbigfrag = (unsigned short*)take((size_t)49152 * 2);
  float* bfold = (float*)take((size_t)64 * 4);
  float* asrc_i = (float*)take((size_t)N_NODES * 16 * 4);
  float* adst_i = (float*)take((size_t)N_NODES * 16 * 4);
  float* asrc_t = (float*)take((size_t)N_NODES * 16 * 4);
  float* adst_t = (float*)take((size_t)N_NODES * 16 * 4);
  int* rowptr_i = (int*)take((size_t)(N_NODES + 1) * 4);
  int* rowptr_t = (int*)take((size_t)(N_NODES + 1) * 4);
  int* fill_i = (int*)take((size_t)N_NODES * 4);
  int* fill_t = (int*)take((size_t)N_NODES * 4);
  int* tmp_i = (int*)take((size_t)N_NODES * 4);
  int* tmp_t = (int*)take((size_t)N_NODES * 4);
  int* csums = (int*)take((size_t)2 * 128 * 4);
  int* srcs_i = (int*)take((size_t)N_EDGES * 4);
  int* srcs_t = (int*)take((size_t)N_EDGES * 4);
  float* gsum = (float*)take((size_t)NG * 16 * 4);
  int* gcnt = (int*)take((size_t)NG * 4);

  // k_prep also zeroes fill_i/fill_t/gsum/gcnt (ranges after weight prep)
  int prep_items = 1280 + 49152 + 64 + N_NODES + N_NODES + NG * 16 + NG;
  k_prep<<<(prep_items + 255) / 256, 256, 0, stream>>>(
      W_i, as_i, ad_i, W_t, as_t, ad_t, Wf, bf, b_i, b_t,
      wsall, wbigfrag, bfold, fill_i, fill_t, gsum, gcnt);

  k_alpha<<<N_NODES / 16, 256, 0, stream>>>(x, wsall, xpad,
                                            asrc_i, adst_i, asrc_t, adst_t);

  dim3 egrid((N_EDGES + 255) / 256, 2);
  k_hist<<<egrid, 256, 0, stream>>>(ei_i, ei_t, fill_i, fill_t);
  dim3 sgrid(NCHUNK, 2);
  k_scan1<<<sgrid, 256, 0, stream>>>(fill_i, fill_t, tmp_i, tmp_t, csums);
  k_scan3<<<sgrid, 256, 0, stream>>>(tmp_i, tmp_t, csums, rowptr_i, rowptr_t,
                                     fill_i, fill_t);
  k_scatter<<<egrid, 256, 0, stream>>>(ei_i, ei_t, fill_i, fill_t, srcs_i, srcs_t);

  k_gat<<<N_NODES / 4, 256, 0, stream>>>(xpad, asrc_i, adst_i, asrc_t, adst_t,
                                         rowptr_i, srcs_i, rowptr_t, srcs_t,
                                         xagg);

  k_mlp<<<(N_NODES + 63) / 64, 256, 0, stream>>>(xagg, wbigfrag, bfold,
                                                 W1, b1, W2, b2, W3, b3,
                                                 batch, gsum, gcnt);

  k_head<<<1, 384, 0, stream>>>(gsum, gcnt, Wce, bce, Wcv, bcv, (float*)d_out);
}

// Round 6
// 158.217 us; speedup vs baseline: 1.7383x; 1.3349x over previous
//
#include <hip/hip_runtime.h>
#include <math.h>

#define N_NODES 20000
#define N_EDGES 320000
#define NG 64
#define NEG 0.2f
#define NCHUNK ((N_NODES + 255) / 256)   // 79

typedef __attribute__((ext_vector_type(8))) short bf16x8;
typedef __attribute__((ext_vector_type(4))) float f32x4;

__device__ __forceinline__ unsigned short f2bf(float f) {
  unsigned int u = __float_as_uint(f);
  return (unsigned short)((u + 0x7fffu + ((u >> 16) & 1u)) >> 16);
}

// ---------------------------------------------------------------------------
// k_prep (one kernel, index ranges):
//  [0,1280)        wsall[20][64]: folded alpha weights (set, role, head)
//  [..+49152)      wbigfrag: bf16 MFMA B-fragments of Wbig[768][64]
//  block 197       bfold[64] = bf + concat(b_i,b_t) @ Wf (cooperative)
//  then            zero fill_i / fill_t / gsum / gcnt
// ---------------------------------------------------------------------------
__global__ __launch_bounds__(256) void k_prep(
    const float* __restrict__ W_i, const float* __restrict__ as_i, const float* __restrict__ ad_i,
    const float* __restrict__ W_t, const float* __restrict__ as_t, const float* __restrict__ ad_t,
    const float* __restrict__ Wf, const float* __restrict__ bf,
    const float* __restrict__ b_i, const float* __restrict__ b_t,
    float* __restrict__ wsall, unsigned short* __restrict__ wbigfrag,
    float* __restrict__ bfold,
    int* __restrict__ fill_i, int* __restrict__ fill_t,
    float* __restrict__ gsum, int* __restrict__ gcnt) {
  __shared__ float bred[4][64];
  int idx = blockIdx.x * 256 + threadIdx.x;
  if (idx < 1280) {
    int k = idx >> 6, c = idx & 63;
    int set = c >> 5, role = (c >> 4) & 1, h = c & 15;
    const float* W = set ? W_t : W_i;
    const float* a = set ? (role ? ad_t : as_t) : (role ? ad_i : as_i);
    float v = 0.f;
#pragma unroll
    for (int j = 0; j < 16; ++j) v = fmaf(W[k * 256 + h * 16 + j], a[h * 16 + j], v);
    wsall[idx] = v;
    return;
  }
  idx -= 1280;
  if (idx < 49152) {
    int ct = idx / 12288, rem = idx % 12288;
    int lane = (rem >> 3) & 63, j = rem & 7, ks = rem >> 9;
    int k = ks * 32 + ((lane >> 4) << 3) + j;
    int nc = ct * 16 + (lane & 15);
    float v = 0.f;
    int g = (k >= 384) ? 1 : 0;
    int r = k - g * 384;
    int h = r / 24, c = r - h * 24;
    if (c < 20) {
      const float* W = g ? W_t : W_i;
      const float* wr = W + c * 256 + (h << 4);
      const float* wf = Wf + ((g << 8) + (h << 4)) * 64 + nc;
#pragma unroll
      for (int m = 0; m < 16; ++m) v = fmaf(wr[m], wf[m * 64], v);
    }
    wbigfrag[idx] = f2bf(v);
    return;
  }
  idx -= 49152;
  if (idx < 256) {
    // block 197 exactly: cooperative bfold (4 waves x 128 rows each)
    int t = threadIdx.x, wv = t >> 6, j = t & 63;
    float p = 0.f;
    int i0 = wv * 128;
#pragma unroll 4
    for (int i = i0; i < i0 + 128; ++i) {
      float b = (i < 256) ? b_i[i] : b_t[i - 256];
      p = fmaf(b, Wf[i * 64 + j], p);
    }
    bred[wv][j] = p;
    __syncthreads();
    if (wv == 0) bfold[j] = bred[0][j] + bred[1][j] + bred[2][j] + bred[3][j] + bf[j];
    return;
  }
  idx -= 256;
  if (idx < N_NODES) { fill_i[idx] = 0; return; }
  idx -= N_NODES;
  if (idx < N_NODES) { fill_t[idx] = 0; return; }
  idx -= N_NODES;
  if (idx < NG * 16) { gsum[idx] = 0.f; return; }
  idx -= NG * 16;
  if (idx < NG) gcnt[idx] = 0;
}

// ---------------------------------------------------------------------------
// k_alpha: 16 nodes/block. asrc/adst (both sets) = x @ wsall; writes xpad.
// ---------------------------------------------------------------------------
__global__ __launch_bounds__(256) void k_alpha(
    const float* __restrict__ x, const float* __restrict__ wsall,
    float* __restrict__ xpad,
    float* __restrict__ asrc0, float* __restrict__ adst0,
    float* __restrict__ asrc1, float* __restrict__ adst1) {
  int t = threadIdx.x;
  int n0 = blockIdx.x * 16;
  __shared__ float xs[16][20];
  __shared__ float ws[20][64];
  for (int i = t; i < 16 * 20; i += 256) {
    int nd = i / 20, k = i % 20;
    xs[nd][k] = x[(n0 + nd) * 20 + k];
  }
  for (int i = t; i < 1280; i += 256) ws[i >> 6][i & 63] = wsall[i];
  __syncthreads();
  for (int i = t; i < 512; i += 256) {
    int nd = i >> 5, j = i & 31;
    xpad[(size_t)(n0 + nd) * 32 + j] = (j < 20) ? xs[nd][j] : 0.f;
  }
#pragma unroll
  for (int i = 0; i < 4; ++i) {
    int wi = i * 256 + t;
    int nd = wi >> 6, c = wi & 63;
    float v = 0.f;
#pragma unroll
    for (int k = 0; k < 20; ++k) v = fmaf(xs[nd][k], ws[k][c], v);
    int n = n0 + nd, h = c & 15;
    float* arr = (c >> 5) ? ((c >> 4) & 1 ? adst1 : asrc1)
                          : ((c >> 4) & 1 ? adst0 : asrc0);
    arr[n * 16 + h] = v;
  }
}

// ---------------------------------------------------------------------------
// CSR build
// ---------------------------------------------------------------------------
__global__ void k_hist(const int* __restrict__ ei0, const int* __restrict__ ei1,
                       int* __restrict__ cnt0, int* __restrict__ cnt1) {
  int e = blockIdx.x * blockDim.x + threadIdx.x;
  if (e >= N_EDGES) return;
  if (blockIdx.y == 0)
    atomicAdd(&cnt0[ei0[N_EDGES + e]], 1);
  else
    atomicAdd(&cnt1[ei1[N_EDGES + e]], 1);
}

__global__ __launch_bounds__(256) void k_scan1(
    const int* __restrict__ cnt0, const int* __restrict__ cnt1,
    int* __restrict__ tmp0, int* __restrict__ tmp1, int* __restrict__ csums) {
  int chunk = blockIdx.x, set = blockIdx.y;
  const int* cnt = set ? cnt1 : cnt0;
  int* tmp = set ? tmp1 : tmp0;
  int t = threadIdx.x, lane = t & 63, wv = t >> 6;
  int i = chunk * 256 + t;
  int v = (i < N_NODES) ? cnt[i] : 0;
  int s = v;
#pragma unroll
  for (int d = 1; d < 64; d <<= 1) {
    int o = __shfl_up(s, d);
    if (lane >= d) s += o;
  }
  __shared__ int wsum[4];
  if (lane == 63) wsum[wv] = s;
  __syncthreads();
  int pre = 0;
#pragma unroll
  for (int j = 0; j < 4; ++j)
    if (j < wv) pre += wsum[j];
  s += pre;
  if (i < N_NODES) tmp[i] = s;
  if (t == 255) csums[set * 128 + chunk] = s;
}

__global__ __launch_bounds__(256) void k_scan3(
    const int* __restrict__ tmp0, const int* __restrict__ tmp1,
    const int* __restrict__ csums,
    int* __restrict__ rp0, int* __restrict__ rp1,
    int* __restrict__ fill0, int* __restrict__ fill1) {
  int chunk = blockIdx.x, set = blockIdx.y;
  const int* tmp = set ? tmp1 : tmp0;
  int* rp = set ? rp1 : rp0;
  int* fill = set ? fill1 : fill0;
  __shared__ int soff;
  if (threadIdx.x == 0) {
    int acc = 0;
    for (int cc = 0; cc < chunk; ++cc) acc += csums[set * 128 + cc];
    soff = acc;
  }
  __syncthreads();
  int off = soff;
  int i = chunk * 256 + threadIdx.x;
  if (i >= N_NODES) return;
  int incl = tmp[i];
  int c = fill[i];
  int excl = off + incl - c;
  rp[i] = excl;
  fill[i] = excl;
  if (i == N_NODES - 1) rp[N_NODES] = off + incl;
}

__global__ void k_scatter(const int* __restrict__ ei0, const int* __restrict__ ei1,
                          int* __restrict__ fill0, int* __restrict__ fill1,
                          unsigned short* __restrict__ srcs0,
                          unsigned short* __restrict__ srcs1) {
  int e = blockIdx.x * blockDim.x + threadIdx.x;
  if (e >= N_EDGES) return;
  const int* ei = blockIdx.y ? ei1 : ei0;
  int* fill = blockIdx.y ? fill1 : fill0;
  unsigned short* srcs = blockIdx.y ? srcs1 : srcs0;
  int d = ei[N_EDGES + e];
  int pos = atomicAdd(&fill[d], 1);
  srcs[pos] = (unsigned short)ei[e];
}

// ---------------------------------------------------------------------------
// k_gat: ONE WAVE PER (node, set). 8-edge batches, 2-level software pipeline
// (srcs 2 batches ahead, asrc/xpad 1 batch ahead). Per batch: lane (e4,h16)
// computes 2 exps, stages attn + x-float2 to a per-wave LDS region
// (wave-synchronous, no __syncthreads), then accumulates 8 edges via
// broadcast ds_read_b128 x2 + b32 (3 DS ops/edge vs 9 shfl).
// Writes normalized xagg (bf16, [N][2][16][24]).
// ---------------------------------------------------------------------------
__global__ __launch_bounds__(256) void k_gat(
    const float* __restrict__ xpad,
    const float* __restrict__ asrc0, const float* __restrict__ adst0,
    const float* __restrict__ asrc1, const float* __restrict__ adst1,
    const int* __restrict__ rp0, const unsigned short* __restrict__ srcs0,
    const int* __restrict__ rp1, const unsigned short* __restrict__ srcs1,
    unsigned short* __restrict__ xagg) {
  __shared__ float lds[4][416];  // per wave: xs[8][36] floats + at[8][16]
  int w4 = threadIdx.x >> 6, lane = threadIdx.x & 63;
  int n = blockIdx.x * 2 + (w4 >> 1);
  int g = w4 & 1;
  int h16 = lane & 15, e4 = lane >> 4;
  float* lxs = lds[w4];
  float* lat = lds[w4] + 288;

  const float* asrc = g ? asrc1 : asrc0;
  const float* adst = g ? adst1 : adst0;
  const int* rp = g ? rp1 : rp0;
  const unsigned short* srcs = g ? srcs1 : srcs0;
  int k0 = rp[n], k1 = rp[n + 1];
  int deg = k1 - k0;
  float adn = adst[n * 16 + h16];
  float lacc = 0.f;
  float xa[8];
#pragma unroll
  for (int j = 0; j < 8; ++j) xa[j] = 0.f;

  if (deg > 0) {
    int nbat = (deg + 7) >> 3;
    // pipeline state: batch b data (av0*, xv0*), batch b+1 srcs (s1*)
    int s0a = (int)srcs[min(k0 + e4, k1 - 1)];
    int s0b = (int)srcs[min(k0 + 4 + e4, k1 - 1)];
    float av0a = asrc[s0a * 16 + h16];
    float av0b = asrc[s0b * 16 + h16];
    float2 xv0a = *(const float2*)&xpad[(size_t)s0a * 32 + h16 * 2];
    float2 xv0b = *(const float2*)&xpad[(size_t)s0b * 32 + h16 * 2];
    int s1a = 0, s1b = 0;
    if (nbat > 1) {
      s1a = (int)srcs[min(k0 + 8 + e4, k1 - 1)];
      s1b = (int)srcs[min(k0 + 12 + e4, k1 - 1)];
    }
    for (int bb = 0; bb < nbat; ++bb) {
      // issue next-level loads before compute
      float av1a = 0.f, av1b = 0.f;
      float2 xv1a = {0.f, 0.f}, xv1b = {0.f, 0.f};
      int s2a = 0, s2b = 0;
      if (bb + 1 < nbat) {
        av1a = asrc[s1a * 16 + h16];
        av1b = asrc[s1b * 16 + h16];
        xv1a = *(const float2*)&xpad[(size_t)s1a * 32 + h16 * 2];
        xv1b = *(const float2*)&xpad[(size_t)s1b * 32 + h16 * 2];
      }
      if (bb + 2 < nbat) {
        int kb = k0 + (bb + 2) * 8;
        s2a = (int)srcs[min(kb + e4, k1 - 1)];
        s2b = (int)srcs[min(kb + 4 + e4, k1 - 1)];
      }
      // compute batch bb
      int base = k0 + bb * 8;
      float a1 = av0a + adn; a1 = a1 >= 0.f ? a1 : NEG * a1;
      float a2 = av0b + adn; a2 = a2 >= 0.f ? a2 : NEG * a2;
      float exa = (base + e4 < k1) ? __expf(a1) : 0.f;
      float exb = (base + 4 + e4 < k1) ? __expf(a2) : 0.f;
      lacc += exa + exb;
      lat[e4 * 16 + h16] = exa;
      lat[(4 + e4) * 16 + h16] = exb;
      *(float2*)&lxs[e4 * 36 + h16 * 2] = xv0a;
      *(float2*)&lxs[(4 + e4) * 36 + h16 * 2] = xv0b;
#pragma unroll
      for (int e = 0; e < 8; ++e) {
        float w = lat[e * 16 + h16];
        const float4 x0 = *(const float4*)&lxs[e * 36 + e4 * 8];
        const float4 x1 = *(const float4*)&lxs[e * 36 + e4 * 8 + 4];
        xa[0] = fmaf(w, x0.x, xa[0]); xa[1] = fmaf(w, x0.y, xa[1]);
        xa[2] = fmaf(w, x0.z, xa[2]); xa[3] = fmaf(w, x0.w, xa[3]);
        xa[4] = fmaf(w, x1.x, xa[4]); xa[5] = fmaf(w, x1.y, xa[5]);
        xa[6] = fmaf(w, x1.z, xa[6]); xa[7] = fmaf(w, x1.w, xa[7]);
      }
      av0a = av1a; av0b = av1b; xv0a = xv1a; xv0b = xv1b;
      s0a = s1a; s0b = s1b; s1a = s2a; s1b = s2b;
    }
  }
  // per-head denom: sum over the 4 e4-groups (lanes differ in bits 4-5)
  float lh = lacc + __shfl_xor(lacc, 16);
  lh += __shfl_xor(lh, 32);
  float invl = lh > 0.f ? 1.f / lh : 0.f;
  if (e4 < 3) {
    unsigned int u[4];
#pragma unroll
    for (int q = 0; q < 4; ++q)
      u[q] = (unsigned int)f2bf(xa[2 * q] * invl) |
             ((unsigned int)f2bf(xa[2 * q + 1] * invl) << 16);
    *(uint4*)&xagg[(size_t)n * 768 + g * 384 + h16 * 24 + e4 * 8] = *(uint4*)u;
  }
}

// ---------------------------------------------------------------------------
// k_mlp: 64 nodes/block. Layer 1: [N,768]@Wbig via bf16 MFMA (24 K-steps,
// 4 col-tiles). Layers 2-4 scalar from LDS; pool via per-block atomics.
// ---------------------------------------------------------------------------
__global__ __launch_bounds__(256) void k_mlp(
    const unsigned short* __restrict__ xagg, const unsigned short* __restrict__ wbigfrag,
    const float* __restrict__ bfold,
    const float* __restrict__ W1m, const float* __restrict__ b1v,
    const float* __restrict__ W2m, const float* __restrict__ b2v,
    const float* __restrict__ W3m, const float* __restrict__ b3v,
    const int* __restrict__ batch,
    float* __restrict__ gsum, int* __restrict__ gcnt) {
  int t = threadIdx.x, w = t >> 6, lane = t & 63;
  int n0 = blockIdx.x * 64;
  __shared__ float o1[64][68];
  __shared__ float o2[64][36];
  __shared__ float o3[64][20];
  __shared__ float o4[64][17];
  __shared__ int bs[64];
  if (t < 64) bs[t] = batch[min(n0 + t, N_NODES - 1)];

  {
    int m = lane & 15, kb = lane >> 4;
    int arow = n0 + w * 16 + m;
    if (arow >= N_NODES) arow = N_NODES - 1;
    const unsigned short* aptr = xagg + (size_t)arow * 768 + kb * 8;
    f32x4 acc0 = {0.f, 0.f, 0.f, 0.f}, acc1 = acc0, acc2 = acc0, acc3 = acc0;
#pragma unroll 4
    for (int ks = 0; ks < 24; ++ks) {
      bf16x8 af = *(const bf16x8*)(aptr + ks * 32);
      const unsigned short* bks = wbigfrag + (size_t)ks * 512 + lane * 8;
      bf16x8 b0 = *(const bf16x8*)(bks);
      bf16x8 b1 = *(const bf16x8*)(bks + 12288);
      bf16x8 b2 = *(const bf16x8*)(bks + 24576);
      bf16x8 b3 = *(const bf16x8*)(bks + 36864);
      acc0 = __builtin_amdgcn_mfma_f32_16x16x32_bf16(af, b0, acc0, 0, 0, 0);
      acc1 = __builtin_amdgcn_mfma_f32_16x16x32_bf16(af, b1, acc1, 0, 0, 0);
      acc2 = __builtin_amdgcn_mfma_f32_16x16x32_bf16(af, b2, acc2, 0, 0, 0);
      acc3 = __builtin_amdgcn_mfma_f32_16x16x32_bf16(af, b3, acc3, 0, 0, 0);
    }
    int col = lane & 15, rg = lane >> 4;
#pragma unroll
    for (int r = 0; r < 4; ++r) {
      int row = w * 16 + rg * 4 + r;
      o1[row][col]      = fmaxf(acc0[r] + bfold[col], 0.f);
      o1[row][16 + col] = fmaxf(acc1[r] + bfold[16 + col], 0.f);
      o1[row][32 + col] = fmaxf(acc2[r] + bfold[32 + col], 0.f);
      o1[row][48 + col] = fmaxf(acc3[r] + bfold[48 + col], 0.f);
    }
  }
  __syncthreads();
  int nd = t >> 2, qo = t & 3;
  {
    float a[8];
#pragma unroll
    for (int j = 0; j < 8; ++j) a[j] = b1v[qo * 8 + j];
#pragma unroll 4
    for (int k = 0; k < 64; ++k) {
      float hv = o1[nd][k];
      const float4 wA = *(const float4*)&W1m[k * 32 + qo * 8];
      const float4 wB = *(const float4*)&W1m[k * 32 + qo * 8 + 4];
      a[0] = fmaf(hv, wA.x, a[0]); a[1] = fmaf(hv, wA.y, a[1]);
      a[2] = fmaf(hv, wA.z, a[2]); a[3] = fmaf(hv, wA.w, a[3]);
      a[4] = fmaf(hv, wB.x, a[4]); a[5] = fmaf(hv, wB.y, a[5]);
      a[6] = fmaf(hv, wB.z, a[6]); a[7] = fmaf(hv, wB.w, a[7]);
    }
#pragma unroll
    for (int j = 0; j < 8; ++j) o2[nd][qo * 8 + j] = fmaxf(a[j], 0.f);
  }
  __syncthreads();
  {
    float a[4];
    const float4 bb = *(const float4*)&b2v[qo * 4];
    a[0] = bb.x; a[1] = bb.y; a[2] = bb.z; a[3] = bb.w;
#pragma unroll 4
    for (int k = 0; k < 32; ++k) {
      float hv = o2[nd][k];
      const float4 ww = *(const float4*)&W2m[k * 16 + qo * 4];
      a[0] = fmaf(hv, ww.x, a[0]); a[1] = fmaf(hv, ww.y, a[1]);
      a[2] = fmaf(hv, ww.z, a[2]); a[3] = fmaf(hv, ww.w, a[3]);
    }
#pragma unroll
    for (int j = 0; j < 4; ++j) o3[nd][qo * 4 + j] = fmaxf(a[j], 0.f);
  }
  __syncthreads();
  {
    float a[4];
    const float4 bb = *(const float4*)&b3v[qo * 4];
    a[0] = bb.x; a[1] = bb.y; a[2] = bb.z; a[3] = bb.w;
#pragma unroll
    for (int k = 0; k < 16; ++k) {
      float hv = o3[nd][k];
      const float4 ww = *(const float4*)&W3m[k * 16 + qo * 4];
      a[0] = fmaf(hv, ww.x, a[0]); a[1] = fmaf(hv, ww.y, a[1]);
      a[2] = fmaf(hv, ww.z, a[2]); a[3] = fmaf(hv, ww.w, a[3]);
    }
#pragma unroll
    for (int j = 0; j < 4; ++j) o4[nd][qo * 4 + j] = fmaxf(a[j], 0.f);
  }
  __syncthreads();
  if (t < 128) {
    int s = t >> 4, js = t & 15;
    int b = bs[0] + s;
    if (b <= bs[63]) {
      float sum = 0.f; int c = 0;
#pragma unroll 8
      for (int ndd = 0; ndd < 64; ++ndd) {
        if (n0 + ndd < N_NODES && bs[ndd] == b) { sum += o4[ndd][js]; ++c; }
      }
      if (c > 0) {
        atomicAdd(&gsum[b * 16 + js], sum);
        if (js == 0) atomicAdd(&gcnt[b], c);
      }
    }
  }
}

__global__ void k_head(const float* __restrict__ gsum, const int* __restrict__ gcnt,
                       const float* __restrict__ Wce, const float* __restrict__ bce,
                       const float* __restrict__ Wcv, const float* __restrict__ bcv,
                       float* __restrict__ out) {
  int t = threadIdx.x;
  if (t >= 384) return;
  int half = t / 192, idx = t % 192;
  int b = idx / 3, r = idx % 3;
  float cnt = (float)gcnt[b];
  float inv = cnt > 0.f ? 1.f / cnt : 1.f;
  const float* Wc = half ? Wcv : Wce;
  const float* bc = half ? bcv : bce;
  float v = bc[r];
#pragma unroll
  for (int j = 0; j < 16; ++j) v = fmaf(gsum[b * 16 + j] * inv, Wc[j * 3 + r], v);
  out[t] = v;
}

extern "C" void kernel_launch(void* const* d_in, const int* in_sizes, int n_in,
                              void* d_out, int out_size, void* d_ws, size_t ws_size,
                              hipStream_t stream) {
  const float* x = (const float*)d_in[0];
  const int* ei_i = (const int*)d_in[1];
  const int* ei_t = (const int*)d_in[3];
  const int* batch = (const int*)d_in[5];
  const float* W_i = (const float*)d_in[6];
  const float* as_i = (const float*)d_in[7];
  const float* ad_i = (const float*)d_in[8];
  const float* b_i = (const float*)d_in[9];
  const float* W_t = (const float*)d_in[10];
  const float* as_t = (const float*)d_in[11];
  const float* ad_t = (const float*)d_in[12];
  const float* b_t = (const float*)d_in[13];
  const float* Wf = (const float*)d_in[14];
  const float* bf = (const float*)d_in[15];
  const float* W1 = (const float*)d_in[16];
  const float* b1 = (const float*)d_in[17];
  const float* W2 = (const float*)d_in[18];
  const float* b2 = (const float*)d_in[19];
  const float* W3 = (const float*)d_in[20];
  const float* b3 = (const float*)d_in[21];
  const float* Wce = (const float*)d_in[22];
  const float* bce = (const float*)d_in[23];
  const float* Wcv = (const float*)d_in[24];
  const float* bcv = (const float*)d_in[25];

  char* ws = (char*)d_ws;
  size_t off = 0;
  auto take = [&](size_t bytes) {
    void* p = ws + off;
    off = (off + bytes + 255) & ~(size_t)255;
    return p;
  };
  float* xpad = (float*)take((size_t)N_NODES * 32 * 4);
  unsigned short* xagg = (unsigned short*)take((size_t)N_NODES * 768 * 2);
  float* wsall = (float*)take((size_t)1280 * 4);
  unsigned short* wbigfrag = (unsigned short*)take((size_t)49152 * 2);
  float* bfold = (float*)take((size_t)64 * 4);
  float* asrc_i = (float*)take((size_t)N_NODES * 16 * 4);
  float* adst_i = (float*)take((size_t)N_NODES * 16 * 4);
  float* asrc_t = (float*)take((size_t)N_NODES * 16 * 4);
  float* adst_t = (float*)take((size_t)N_NODES * 16 * 4);
  int* rowptr_i = (int*)take((size_t)(N_NODES + 1) * 4);
  int* rowptr_t = (int*)take((size_t)(N_NODES + 1) * 4);
  int* fill_i = (int*)take((size_t)N_NODES * 4);
  int* fill_t = (int*)take((size_t)N_NODES * 4);
  int* tmp_i = (int*)take((size_t)N_NODES * 4);
  int* tmp_t = (int*)take((size_t)N_NODES * 4);
  int* csums = (int*)take((size_t)2 * 128 * 4);
  unsigned short* srcs_i = (unsigned short*)take((size_t)N_EDGES * 2);
  unsigned short* srcs_t = (unsigned short*)take((size_t)N_EDGES * 2);
  float* gsum = (float*)take((size_t)NG * 16 * 4);
  int* gcnt = (int*)take((size_t)NG * 4);

  int prep_items = 1280 + 49152 + 256 + N_NODES + N_NODES + NG * 16 + NG;
  k_prep<<<(prep_items + 255) / 256, 256, 0, stream>>>(
      W_i, as_i, ad_i, W_t, as_t, ad_t, Wf, bf, b_i, b_t,
      wsall, wbigfrag, bfold, fill_i, fill_t, gsum, gcnt);

  k_alpha<<<N_NODES / 16, 256, 0, stream>>>(x, wsall, xpad,
                                            asrc_i, adst_i, asrc_t, adst_t);

  dim3 egrid((N_EDGES + 255) / 256, 2);
  k_hist<<<egrid, 256, 0, stream>>>(ei_i, ei_t, fill_i, fill_t);
  dim3 sgrid(NCHUNK, 2);
  k_scan1<<<sgrid, 256, 0, stream>>>(fill_i, fill_t, tmp_i, tmp_t, csums);
  k_scan3<<<sgrid, 256, 0, stream>>>(tmp_i, tmp_t, csums, rowptr_i, rowptr_t,
                                     fill_i, fill_t);
  k_scatter<<<egrid, 256, 0, stream>>>(ei_i, ei_t, fill_i, fill_t, srcs_i, srcs_t);

  k_gat<<<N_NODES / 2, 256, 0, stream>>>(xpad, asrc_i, adst_i, asrc_t, adst_t,
                                         rowptr_i, srcs_i, rowptr_t, srcs_t,
                                         xagg);

  k_mlp<<<(N_NODES + 63) / 64, 256, 0, stream>>>(xagg, wbigfrag, bfold,
                                                 W1, b1, W2, b2, W3, b3,
                                                 batch, gsum, gcnt);

  k_head<<<1, 384, 0, stream>>>(gsum, gcnt, Wce, bce, Wcv, bcv, (float*)d_out);
}